// Round 5
// baseline (59.597 us; speedup 1.0000x reference)
//
#include <hip/hip_runtime.h>

// Segmented histogram: out[g, c] = sum of w[i] for i in [ptr[g], ptr[g+1])
// with x[i] == c < out_dim.
//
// Rounds 1-4 lesson: any one-burst-per-block structure is duty-cycle limited to
// ~1.3 TB/s because the first __syncthreads drains vmcnt(0) and blocks wait out
// the full memory latency once per lifetime. This version has NO barriers and
// NO vmcnt drains in the hot loop:
//   - per-WAVE private LDS histogram (1 KB/wave, no cross-wave sync)
//   - persistent waves grid-stride over 512-node ranges, register
//     double-buffered (next range's 4x dwordx4 issued before binning current)
//   - all ptr[] reads in the graph walk forced to s_load (scalar path,
//     lgkmcnt) so they can't drain the vmcnt FIFO holding the prefetch
//   - flush straight to global: direct store for graphs wholly inside a range
//     (exclusive by construction), atomicAdd of nonzero bins otherwise, onto
//     hipMemsetAsync-zeroed output (also handles empty graphs).

#define NPT   8                 // nodes per lane
#define WR    (64 * NPT)        // 512 nodes per wave-range
#define ODIM  256
#define NBLK  1536              // 6 blocks/CU, 24 waves/CU

// Scalar load ptr[idx] via s_load (lgkmcnt path; never touches vmcnt).
__device__ __forceinline__ int sload_i32(const int* p, int idx) {
    int v;
    asm volatile("s_load_dword %0, %1, %2\n\ts_waitcnt lgkmcnt(0)"
                 : "=&s"(v)
                 : "s"(p), "s"(idx * 4));
    return v;
}

#define LOADR(LA, LB, WA, WB, RR)                                              \
    { const int _base = (RR) * WR + lane * NPT;                                \
      if (_base + NPT <= n_nodes) {                                            \
          LA = *reinterpret_cast<const int4*>(x + _base);                      \
          LB = *reinterpret_cast<const int4*>(x + _base + 4);                  \
          WA = *reinterpret_cast<const float4*>(w + _base);                    \
          WB = *reinterpret_cast<const float4*>(w + _base + 4);                \
      } else {                                                                 \
          int _l[8]; float _w[8];                                              \
          _Pragma("unroll")                                                    \
          for (int _k = 0; _k < 8; ++_k) {                                     \
              if (_base + _k < n_nodes) { _l[_k] = x[_base + _k];              \
                                          _w[_k] = w[_base + _k]; }            \
              else { _l[_k] = 0x7fffffff; _w[_k] = 0.0f; }                     \
          }                                                                    \
          LA = make_int4(_l[0], _l[1], _l[2], _l[3]);                          \
          LB = make_int4(_l[4], _l[5], _l[6], _l[7]);                          \
          WA = make_float4(_w[0], _w[1], _w[2], _w[3]);                        \
          WB = make_float4(_w[4], _w[5], _w[6], _w[7]);                        \
      } }

#define ADDK(LBL, WV, K)                                                       \
    { const int _n = nbase + (K);                                              \
      if (_n >= s && _n < e && (unsigned)(LBL) < (unsigned)ODIM)               \
          atomicAdd(&h[LBL], (WV)); }

#define BINR(LA, LB, WA, WB, RR)                                               \
    { const int r0 = __builtin_amdgcn_readfirstlane((RR) * WR);                \
      const int r1 = min(r0 + WR, n_nodes);                                    \
      const int nbase = r0 + lane * NPT;                                       \
      /* j = last graph with ptr[j] <= r0 (scalar binary search) */            \
      int lo = 0, hi = num_graphs - 1;                                         \
      while (lo < hi) {                                                        \
          const int mid = (lo + hi + 1) >> 1;                                  \
          if (sload_i32(ptr, mid) <= r0) lo = mid; else hi = mid - 1;          \
      }                                                                        \
      int j = lo;                                                              \
      int pstart = sload_i32(ptr, j);                                          \
      for (;;) {                                                               \
          const int pend = sload_i32(ptr, j + 1);                              \
          const int s = max(pstart, r0);                                       \
          const int e = min(pend, r1);                                         \
          ADDK(LA.x, WA.x, 0) ADDK(LA.y, WA.y, 1)                              \
          ADDK(LA.z, WA.z, 2) ADDK(LA.w, WA.w, 3)                              \
          ADDK(LB.x, WB.x, 4) ADDK(LB.y, WB.y, 5)                              \
          ADDK(LB.z, WB.z, 6) ADDK(LB.w, WB.w, 7)                              \
          const bool whole = (pstart >= r0) && (pend <= r1);                   \
          float* row = out + (size_t)j * ODIM;                                 \
          _Pragma("unroll")                                                    \
          for (int _k = 0; _k < 4; ++_k) {                                     \
              const int bin = lane + 64 * _k;                                  \
              const float v = h[bin];                                          \
              if (whole)          row[bin] = v;                                \
              else if (v != 0.0f) atomicAdd(&row[bin], v);                     \
              h[bin] = 0.0f;                                                   \
          }                                                                    \
          if (pend >= r1) break;                                               \
          ++j; pstart = pend;                                                  \
      } }

extern "C" __global__ __launch_bounds__(256, 6)
void hist_kernel(const int* __restrict__ x, const int* __restrict__ ptr,
                 const float* __restrict__ w, float* __restrict__ out,
                 int n_nodes, int num_graphs) {
    __shared__ float hist[4][ODIM];

    const int wv   = (int)threadIdx.x >> 6;
    const int lane = (int)threadIdx.x & 63;
    float* h = hist[wv];

    // zero this wave's private histogram (no barrier needed: per-wave)
#pragma unroll
    for (int k = 0; k < 4; ++k) h[lane + 64 * k] = 0.0f;

    const int n_ranges = (n_nodes + WR - 1) / WR;
    const int stride   = NBLK * 4;
    int r = (int)blockIdx.x * 4 + wv;

    int4 la_a, lb_a, la_b, lb_b;
    float4 wa_a, wb_a, wa_b, wb_b;

    if (r < n_ranges) LOADR(la_a, lb_a, wa_a, wb_a, r);
    bool useA = true;
    while (r < n_ranges) {
        const int rn = r + stride;
        if (useA) {
            if (rn < n_ranges) LOADR(la_b, lb_b, wa_b, wb_b, rn);
            BINR(la_a, lb_a, wa_a, wb_a, r);
        } else {
            if (rn < n_ranges) LOADR(la_a, lb_a, wa_a, wb_a, rn);
            BINR(la_b, lb_b, wa_b, wb_b, r);
        }
        useA = !useA;
        r = rn;
    }
}

// Generic fallback (round-1 structure) for out_dim != 256.
extern "C" __global__ __launch_bounds__(256)
void seg_hist_fallback(const int* __restrict__ x, const int* __restrict__ ptr,
                       const float* __restrict__ w, float* __restrict__ out,
                       int out_dim) {
    extern __shared__ float fhist[];
    const int g = blockIdx.x;
    const int start = ptr[g];
    const int end = ptr[g + 1];
    for (int c = (int)threadIdx.x; c < out_dim; c += 256) fhist[c] = 0.0f;
    __syncthreads();
    for (int i = start + (int)threadIdx.x; i < end; i += 256) {
        const int lbl = x[i];
        if ((unsigned)lbl < (unsigned)out_dim) atomicAdd(&fhist[lbl], w[i]);
    }
    __syncthreads();
    float* o = out + (size_t)g * (size_t)out_dim;
    for (int c = (int)threadIdx.x; c < out_dim; c += 256) o[c] = fhist[c];
}

extern "C" void kernel_launch(void* const* d_in, const int* in_sizes, int n_in,
                              void* d_out, int out_size, void* d_ws, size_t ws_size,
                              hipStream_t stream) {
    const int* x   = (const int*)d_in[0];
    const int* ptr = (const int*)d_in[1];
    const float* w = (const float*)d_in[2];
    float* out     = (float*)d_out;

    const int n_nodes    = in_sizes[0];
    const int num_graphs = in_sizes[1] - 1;
    const int out_dim    = out_size / num_graphs;

    if (out_dim != ODIM) {
        seg_hist_fallback<<<num_graphs, 256, (size_t)out_dim * sizeof(float), stream>>>(
            x, ptr, w, out, out_dim);
        return;
    }

    // zero output (atomic flushes accumulate onto it; also covers empty graphs)
    hipMemsetAsync(d_out, 0, (size_t)out_size * sizeof(float), stream);

    hist_kernel<<<NBLK, 256, 0, stream>>>(x, ptr, w, out, n_nodes, num_graphs);
}